// Round 20
// baseline (178.836 us; speedup 1.0000x reference)
//
#include <hip/hip_runtime.h>

#define NG 24      // B*GP graphs
#define NB 4       // batch
#define GPg 6      // graphs per sample
#define NN 1024    // nodes
#define DD 128     // feature dim
#define EE 16384   // edges per graph

typedef __bf16 bf16;
typedef __bf16 bf16x8 __attribute__((ext_vector_type(8)));
typedef float f32x4 __attribute__((ext_vector_type(4)));

#define GLOBAL_AS __attribute__((address_space(1)))
#define LDS_AS __attribute__((address_space(3)))

// packed f32 helpers (VOP3P, full-rate dual f32)
__device__ __forceinline__ float2 pk_mul(float2 a, float2 b) {
  float2 d;
  asm("v_pk_mul_f32 %0, %1, %2" : "=v"(d) : "v"(a), "v"(b));
  return d;
}
__device__ __forceinline__ float2 pk_fma(float2 a, float2 b, float2 c) {
  float2 d;
  asm("v_pk_fma_f32 %0, %1, %2, %3" : "=v"(d) : "v"(a), "v"(b), "v"(c));
  return d;
}

// poly bin: w = 10.5*(1+tanh(s)) via deg-7 odd poly, |err(tanh)|<=6e-5 on |s|<=1.05
__device__ __forceinline__ int binidx(float v) {
  float u = v * v;
  float q = fmaf(fmaf(fmaf(-0.261093f, u, 1.222977f), u, -3.463278f), u, 10.49874f);
  return (int)fmaf(v, q, 10.5f);
}

// ---- zero counts+gmat+simsum (111168 B contiguous) ----
__global__ void k_zero(f32x4* __restrict__ p) {
  int i = blockIdx.x * 256 + threadIdx.x;
  if (i < 6948) p[i] = f32x4{0.f, 0.f, 0.f, 0.f};
}

// ---- fused: dst histogram (blocks 0..1535) | weight transpose -> bf16 (1536..1791) ----
__global__ void k_histw(const int* __restrict__ ei, int* __restrict__ counts,
                        const float* __restrict__ gW, const float* __restrict__ Ws,
                        bf16* __restrict__ gwt, bf16* __restrict__ wst) {
  int bid = blockIdx.x;
  if (bid >= 1536) {                     // weight transpose -> bf16
    int i = (bid - 1536) * 256 + threadIdx.x;   // i < 4*128*128
    int c = i >> 14, k = (i >> 7) & 127, j = i & 127;
    gwt[(c << 14) | (j << 7) | k] = (bf16)gW[i];   // gwt[c][j][k] = gW[c][k][j]
    wst[(j << 9) | (c << 7) | k] = (bf16)Ws[i];    // wst[j][c][k] = Ws[c][k][j]
    return;
  }
  int t = bid * 256 + threadIdx.x;       // t < NG*EE
  int g = t >> 14, e = t & (EE - 1);
  int dst = ei[g * 2 * EE + EE + e];
  atomicAdd(&counts[g * NN + dst], 1);
}

// ---------------- per-graph prefix sum (shfl wave-scan, 2 barriers) ----------------
__global__ void k_scan(const int* __restrict__ counts, int* __restrict__ offs,
                       int* __restrict__ cursor) {
  __shared__ int wsum[16];
  int g = blockIdx.x, t = threadIdx.x;   // 1024 threads = 16 waves
  int lane = t & 63, wv = t >> 6;
  int myc = counts[g * NN + t];
  int v = myc;
#pragma unroll
  for (int d = 1; d < 64; d <<= 1) {
    int u = __shfl_up(v, d);
    if (lane >= d) v += u;
  }
  if (lane == 63) wsum[wv] = v;
  __syncthreads();
  if (t < 16) {
    int s = wsum[t];
#pragma unroll
    for (int d = 1; d < 16; d <<= 1) {
      int u = __shfl_up(s, d);
      if (t >= d) s += u;
    }
    wsum[t] = s;                         // inclusive scan of wave sums
  }
  __syncthreads();
  int incl = v + (wv > 0 ? wsum[wv - 1] : 0);
  int excl = incl - myc;
  offs[g * 1025 + t] = excl;
  cursor[g * NN + t] = excl;
  if (t == NN - 1) offs[g * 1025 + NN] = incl;
}

// ---------------- CSR scatter: src index + raw edge weights (vectorized) ----------------
__global__ void k_scatter(const int* __restrict__ ei, const float* __restrict__ ea,
                          int* __restrict__ cursor, int* __restrict__ csrs,
                          float* __restrict__ csre) {
  int t = blockIdx.x * 256 + threadIdx.x;
  if (t >= NG * EE) return;
  int g = t >> 14, e = t & (EE - 1);
  int src = ei[g * 2 * EE + e], dst = ei[g * 2 * EE + EE + e];
  int pos = atomicAdd(&cursor[g * NN + dst], 1);
  size_t idx = (size_t)g * EE + pos;
  csrs[idx] = src;
  const float* p = ea + ((size_t)g * EE + e) * 6;
  float2 q0 = *(const float2*)(p + 2);   // 8B-aligned (24e+8)
  float2 q1 = *(const float2*)(p + 4);
  f32x4 v; v[0] = q0.x; v[1] = q0.y; v[2] = q1.x; v[3] = q1.y;
  *(f32x4*)(csre + idx * 4) = v;
}

// ---------------- per-node degree -> dinv4[g][n][4] (CSR row walk) ----------------
__global__ void k_deg(const int* __restrict__ offs, const float* __restrict__ csre,
                      float* __restrict__ dinv4) {
  int t = blockIdx.x * 256 + threadIdx.x;   // t = ((g*NN)+n)*4+c
  int c = t & 3, n = (t >> 2) & (NN - 1), g = t >> 12;
  int beg = offs[g * 1025 + n], end = offs[g * 1025 + n + 1];
  const float* ep = csre + (size_t)g * EE * 4 + c;
  float s = 1.0f;                            // self loop
  for (int p = beg; p < end; ++p) s += ep[(size_t)p * 4];
  dinv4[t] = rsqrtf(s);
}

// ------- xws[g][n][c*128+j] = dinv4[g][n][c] * (x[g] @ gW[c])[n][j]  (f32 A, bf16 MFMA) -------
__global__ __launch_bounds__(256) void k_xw(const float* __restrict__ x,
                                            const bf16* __restrict__ gwt,
                                            const float* __restrict__ dinv4,
                                            bf16* __restrict__ xw) {
  int bid = blockIdx.x;
  int gc = bid >> 3, mb = bid & 7;
  int g = gc >> 2, c = gc & 3;
  int lane = threadIdx.x & 63, wid = threadIdx.x >> 6;
  int wm = wid >> 1, wn = wid & 1;
  int row0 = mb * 128 + wm * 64, col0 = wn * 64;
  const float* A = x + (size_t)g * NN * DD;
  const bf16* Bt = gwt + (size_t)c * DD * DD;
  int lr = lane & 15, lk = (lane >> 4) * 8;
  f32x4 acc[4][4] = {};
  for (int kc = 0; kc < 128; kc += 32) {
    bf16x8 a[4], b[4];
#pragma unroll
    for (int i2 = 0; i2 < 4; i2++) {
      const f32x4* pa = (const f32x4*)(A + (size_t)(row0 + i2 * 16 + lr) * DD + kc + lk);
      f32x4 f0 = pa[0], f1 = pa[1];
#pragma unroll
      for (int q = 0; q < 4; q++) { a[i2][q] = (bf16)f0[q]; a[i2][4 + q] = (bf16)f1[q]; }
    }
#pragma unroll
    for (int j2 = 0; j2 < 4; j2++)
      b[j2] = *(const bf16x8*)(Bt + (size_t)(col0 + j2 * 16 + lr) * DD + kc + lk);
#pragma unroll
    for (int i2 = 0; i2 < 4; i2++)
#pragma unroll
      for (int j2 = 0; j2 < 4; j2++)
        acc[i2][j2] = __builtin_amdgcn_mfma_f32_16x16x32_bf16(a[i2], b[j2], acc[i2][j2], 0, 0, 0);
  }
  bf16* out = xw + (size_t)g * NN * 512 + c * 128;
  const float* dv = dinv4 + ((size_t)g * NN) * 4 + c;
  int cr = (lane >> 4) * 4, cc = lane & 15;
#pragma unroll
  for (int i2 = 0; i2 < 4; i2++)
#pragma unroll
    for (int r2 = 0; r2 < 4; r2++) {
      int row = row0 + i2 * 16 + cr + r2;
      float dvv = dv[row * 4];
#pragma unroll
      for (int j2 = 0; j2 < 4; j2++)
        out[(size_t)row * 512 + col0 + j2 * 16 + cc] = (bf16)(acc[i2][j2][r2] * dvv);
    }
}

// ---- aggregation: hb[g][n][512] = relu(dinv*(sum ew*xws[src] + xws[n]) + b), 4 ch/wave,
// ---- 4-deep gather pipeline ----
__global__ __launch_bounds__(256) void k_agg(const int* __restrict__ offs, const int* __restrict__ csrs,
                                             const float* __restrict__ csre, const float* __restrict__ dinv4,
                                             const float* __restrict__ gb, const bf16* __restrict__ xw,
                                             bf16* __restrict__ hb) {
  int bid = blockIdx.x;
  int lb = (bid & 7) * (NG * 256 / 8) + (bid >> 3);   // XCD swizzle: 768 blocks (3 graphs) per XCD
  int g = lb >> 8, n4 = lb & 255;
  int wid = threadIdx.x >> 6, lane = threadIdx.x & 63;
  int n = n4 * 4 + wid;
  int c = lane >> 4, d0 = (lane & 15) * 8;
  const bf16* xwg = xw + (size_t)g * NN * 512;
  int beg = offs[g * 1025 + n], end = offs[g * 1025 + n + 1];
  const int* sp = csrs + (size_t)g * EE;
  const float* ep = csre + (size_t)g * EE * 4;
  float dvn = dinv4[((size_t)g * NN + n) * 4 + c];
  float acc[8] = {};
  int p = beg;
  for (; p + 3 < end; p += 4) {
    int s0 = sp[p], s1 = sp[p + 1], s2 = sp[p + 2], s3 = sp[p + 3];
    float w0 = ep[(size_t)p * 4 + c];
    float w1 = ep[(size_t)(p + 1) * 4 + c];
    float w2 = ep[(size_t)(p + 2) * 4 + c];
    float w3 = ep[(size_t)(p + 3) * 4 + c];
    bf16x8 v0 = *(const bf16x8*)(xwg + (size_t)s0 * 512 + lane * 8);
    bf16x8 v1 = *(const bf16x8*)(xwg + (size_t)s1 * 512 + lane * 8);
    bf16x8 v2 = *(const bf16x8*)(xwg + (size_t)s2 * 512 + lane * 8);
    bf16x8 v3 = *(const bf16x8*)(xwg + (size_t)s3 * 512 + lane * 8);
#pragma unroll
    for (int q = 0; q < 8; q++)
      acc[q] += w0 * (float)v0[q] + w1 * (float)v1[q] + w2 * (float)v2[q] + w3 * (float)v3[q];
  }
  for (; p < end; ++p) {
    int s0 = sp[p];
    float w0 = ep[(size_t)p * 4 + c];
    bf16x8 v0 = *(const bf16x8*)(xwg + (size_t)s0 * 512 + lane * 8);
#pragma unroll
    for (int q = 0; q < 8; q++) acc[q] += w0 * (float)v0[q];
  }
  bf16x8 vs = *(const bf16x8*)(xwg + (size_t)n * 512 + lane * 8);
  bf16x8 o;
#pragma unroll
  for (int q = 0; q < 8; q++) {
    float r2 = dvn * (acc[q] + (float)vs[q]) + gb[c * 128 + d0 + q];
    o[q] = (bf16)fmaxf(r2, 0.f);
  }
  *(bf16x8*)(hb + ((size_t)g * NN + n) * 512 + lane * 8) = o;
}

// ---- fused: x_tmp = hb @ wst (K=512); row-mean -> gmat; row-L2-normalize -> xn (bf16) ----
__global__ __launch_bounds__(256) void k_mixn(const bf16* __restrict__ hb,
                                              const bf16* __restrict__ wst,
                                              float* __restrict__ gmat,
                                              bf16* __restrict__ xn) {
  __shared__ float rowssq[128];
  int bid = blockIdx.x;
  int g = bid >> 3, mb = bid & 7;
  int lane = threadIdx.x & 63, wid = threadIdx.x >> 6;
  int wm = wid >> 1, wn = wid & 1;
  int row0 = mb * 128 + wm * 64, col0 = wn * 64;
  const bf16* H = hb + (size_t)g * NN * 512;
  int lr = lane & 15, lk = (lane >> 4) * 8;
  if (threadIdx.x < 128) rowssq[threadIdx.x] = 0.f;
  f32x4 acc[4][4] = {};
  for (int kc = 0; kc < 512; kc += 32) {
    bf16x8 a[4], b[4];
#pragma unroll
    for (int i2 = 0; i2 < 4; i2++)
      a[i2] = *(const bf16x8*)(H + (size_t)(row0 + i2 * 16 + lr) * 512 + kc + lk);
#pragma unroll
    for (int j2 = 0; j2 < 4; j2++)
      b[j2] = *(const bf16x8*)(wst + (size_t)(col0 + j2 * 16 + lr) * 512 + kc + lk);
#pragma unroll
    for (int i2 = 0; i2 < 4; i2++)
#pragma unroll
      for (int j2 = 0; j2 < 4; j2++)
        acc[i2][j2] = __builtin_amdgcn_mfma_f32_16x16x32_bf16(a[i2], b[j2], acc[i2][j2], 0, 0, 0);
  }
  __syncthreads();                       // rowssq zeros visible
  int cr = (lane >> 4) * 4, cc = lane & 15;
#pragma unroll
  for (int i2 = 0; i2 < 4; i2++)
#pragma unroll
    for (int r2 = 0; r2 < 4; r2++) {
      float s = 0.f;
#pragma unroll
      for (int j2 = 0; j2 < 4; j2++) { float v = acc[i2][j2][r2]; s += v * v; }
#pragma unroll
      for (int d2 = 1; d2 < 16; d2 <<= 1) s += __shfl_xor(s, d2);
      if (cc == 0) atomicAdd(&rowssq[wm * 64 + i2 * 16 + cr + r2], s);
    }
#pragma unroll
  for (int j2 = 0; j2 < 4; j2++) {
    float s = 0.f;
#pragma unroll
    for (int i2 = 0; i2 < 4; i2++)
#pragma unroll
      for (int r2 = 0; r2 < 4; r2++) s += acc[i2][j2][r2];
    s += __shfl_xor(s, 16);
    s += __shfl_xor(s, 32);
    if ((lane >> 4) == 0)
      atomicAdd(&gmat[(g / GPg) * 768 + (g % GPg) * 128 + col0 + j2 * 16 + cc], s * (1.0f / NN));
  }
  __syncthreads();                       // rowssq complete
  bf16* xp = xn + (size_t)g * NN * DD;
#pragma unroll
  for (int i2 = 0; i2 < 4; i2++)
#pragma unroll
    for (int r2 = 0; r2 < 4; r2++) {
      int rowl = wm * 64 + i2 * 16 + cr + r2;
      float inv = 1.0f / fmaxf(sqrtf(rowssq[rowl]), 1e-12f);
#pragma unroll
      for (int j2 = 0; j2 < 4; j2++)
        xp[(size_t)(mb * 128 + rowl) * DD + col0 + j2 * 16 + cc] = (bf16)(acc[i2][j2][r2] * inv);
    }
}

// ---- pairwise sim: (pair, 128-row strip, 16-tile half) per block; 2x8KB LDS dbuf,
// ---- fragment-order LDS (0 conflicts), counted-vmcnt pipeline, diagonal symmetry,
// ---- PACKED (v_pk_fma_f32) poly binning ----
__global__ __launch_bounds__(256, 4) void k_pair(const bf16* __restrict__ xn,
                                                 unsigned* __restrict__ simsum) {
  __shared__ char lds[16384];            // 2 x 8KB B-tile (32 cols x 128 k)
  int bid = blockIdx.x;
  int lb = (bid & 7) * 168 + (bid >> 3); // 1344 = 8*168, bijective XCD swizzle
  int b = lb / 336, rem = lb % 336;
  int pj = rem >> 4, rem2 = rem & 15;
  int s128 = rem2 >> 1, half = rem2 & 1; // 128-row strip, 16-tile half of B range
  int r = pj, i = 0;
  while (r >= 6 - i) { r -= 6 - i; ++i; }
  int j = i + r;
  bool isdiag = (i == j);
  int tb = half * 16, te = tb + 16;
  if (isdiag && 4 * s128 > tb) tb = 4 * s128;   // diagonal: skip tiles below the diagonal
  if (tb >= te) return;                          // empty half
  int lane = threadIdx.x & 63, wid = threadIdx.x >> 6;
  int lr = lane & 15, hi16 = (lane >> 4) * 16;
  const char* Ag = (const char*)(xn + ((size_t)(b * GPg + i) * NN + s128 * 128 + wid * 32) * DD);
  const char* Bg0 = (const char*)(xn + (size_t)(b * GPg + j) * NN * DD);

  // packed-poly constants (splatted into VGPR pairs once)
  const float2 C3 = {-0.261093f, -0.261093f};
  const float2 C2 = {1.222977f, 1.222977f};
  const float2 C1 = {-3.463278f, -3.463278f};
  const float2 C0 = {10.49874f, 10.49874f};
  const float2 HF = {10.5f, 10.5f};

  // A: wave's 32 rows x 128 k in registers, forced-complete before staging (vmcnt bookkeeping)
  bf16x8 a[2][4];
#pragma unroll
  for (int g2 = 0; g2 < 2; g2++)
#pragma unroll
    for (int kc = 0; kc < 4; kc++) {
      a[g2][kc] = *(const bf16x8*)(Ag + (g2 * 16 + lr) * 256 + kc * 64 + hi16);
      asm volatile("" :: "v"(a[g2][kc]));
    }

  // stage 8KB tile tn (32 B-rows x 256B) in fragment order; wave wid owns kc=wid:
  // LDS slot (kc*2048 + j2*1024 + lane*16) <- global row=(j2*16+lr), kbyte=kc*64+hi16
  auto stage = [&](int buf, int tn) {
    const char* src = Bg0 + tn * 8192;
#pragma unroll
    for (int j2 = 0; j2 < 2; ++j2)
      __builtin_amdgcn_global_load_lds(
          (const GLOBAL_AS void*)(src + (j2 * 16 + lr) * 256 + wid * 64 + hi16),
          (LDS_AS void*)(lds + buf * 8192 + wid * 2048 + j2 * 1024), 16, 0, 0);
  };
  stage(0, tb);
  if (tb + 1 < te) stage(1, tb + 1);

  int cnt = 0;
  int cc = lane & 15, cr = (lane >> 4) * 4;
  for (int t = tb; t < te; ++t) {
    int cur = (t - tb) & 1;
    if (t < te - 1) asm volatile("s_waitcnt vmcnt(2)" ::: "memory");  // buf[cur] ready; next in flight
    else            asm volatile("s_waitcnt vmcnt(0)" ::: "memory");
    __builtin_amdgcn_s_barrier();
    const char* Bl = lds + cur * 8192;
    f32x4 acc[2][2] = {};
#pragma unroll
    for (int kc = 0; kc < 4; kc++) {
      bf16x8 bb[2];
#pragma unroll
      for (int j2 = 0; j2 < 2; j2++)
        bb[j2] = *(const bf16x8*)(Bl + kc * 2048 + j2 * 1024 + lane * 16);  // conflict-free
#pragma unroll
      for (int g2 = 0; g2 < 2; g2++)
#pragma unroll
        for (int j2 = 0; j2 < 2; j2++)
          acc[g2][j2] = __builtin_amdgcn_mfma_f32_16x16x32_bf16(a[g2][kc], bb[j2], acc[g2][j2], 0, 0, 0);
    }
    asm volatile("s_waitcnt lgkmcnt(0)" ::: "memory");  // my ds_reads done before buffer reuse
    __builtin_amdgcn_sched_barrier(0);
    __builtin_amdgcn_s_barrier();        // all waves done reading buf[cur]
    if (t + 2 < te) stage(cur, t + 2);   // refill; flight hidden under binning + next MFMA
    if (isdiag && t < 4 * s128 + 4) {    // boundary tiles: per-element 2/1/0 weights (scalar path)
      int tc = 0;
#pragma unroll
      for (int g2 = 0; g2 < 2; g2++)
#pragma unroll
        for (int j2 = 0; j2 < 2; j2++)
#pragma unroll
          for (int r2 = 0; r2 < 4; r2++) {
            int idx = binidx(acc[g2][j2][r2]);
            int lm = t * 32 + j2 * 16 + cc;
            int ln = s128 * 128 + wid * 32 + g2 * 16 + cr + r2;
            tc += (lm > ln) ? 2 * idx : (lm == ln ? idx : 0);
          }
      cnt += tc;
    } else {                             // packed poly: 8 float2 pairs = 16 elems
      int tc = 0;
#pragma unroll
      for (int g2 = 0; g2 < 2; g2++)
#pragma unroll
        for (int j2 = 0; j2 < 2; j2++)
#pragma unroll
          for (int h = 0; h < 2; h++) {
            float2 v; v.x = acc[g2][j2][2 * h]; v.y = acc[g2][j2][2 * h + 1];
            float2 u = pk_mul(v, v);
            float2 q = pk_fma(C3, u, C2);
            q = pk_fma(q, u, C1);
            q = pk_fma(q, u, C0);
            float2 wv = pk_fma(v, q, HF);
            tc += (int)wv.x + (int)wv.y;
          }
      cnt += isdiag ? 2 * tc : tc;       // wave-uniform weight
    }
  }
#pragma unroll
  for (int d2 = 32; d2; d2 >>= 1) cnt += __shfl_xor(cnt, d2);
  if (lane == 0) atomicAdd(&simsum[((size_t)b * GPg + i) * GPg + j], (unsigned)cnt);
}

// ---------------- backnet: 104 length-768 dots, 8 threads each ----------------
__global__ void k_back(const float* __restrict__ gmat, const unsigned* __restrict__ simsum,
                       const float* __restrict__ l1W, const float* __restrict__ l1b,
                       const float* __restrict__ cfW, const float* __restrict__ cfb,
                       const float* __restrict__ l2W, const float* __restrict__ l2b,
                       const float* __restrict__ sfW, const float* __restrict__ sfb,
                       float* __restrict__ out) {
  __shared__ float feat[NB][20];
  __shared__ float strength[NB][GPg];
  __shared__ float simmean[NB][GPg];
  int t = threadIdx.x, g = t >> 3, l = t & 7;
  if (g < 80) {                          // feat: 4x20 dots of length 768
    int b = g / 20, jj = g % 20;
    float s = 0.f;
#pragma unroll 8
    for (int k = l; k < 768; k += 8) s += gmat[b * 768 + k] * l1W[k * 20 + jj];
    s += __shfl_xor(s, 1); s += __shfl_xor(s, 2); s += __shfl_xor(s, 4);
    if (l == 0) {
      float f = fmaxf(s + l1b[jj], 0.f);
      feat[b][jj] = f;
      out[8 + b * 20 + jj] = f;
    }
  } else if (g < 104) {                  // strength: 4x6 dots of length 768
    int q = g - 80, b = q / GPg, pp = q % GPg;
    float s = 0.f;
#pragma unroll 8
    for (int k = l; k < 768; k += 8) s += gmat[b * 768 + k] * l2W[k * GPg + pp];
    s += __shfl_xor(s, 1); s += __shfl_xor(s, 2); s += __shfl_xor(s, 4);
    if (l == 0) strength[b][pp] = s + l2b[pp];
  } else if (t >= 832 && t < 856) {      // simmean from simsum
    int q = t - 832; int b = q / GPg, ii = q % GPg;
    float s = 0.f;
    for (int jj = 0; jj < GPg; jj++) {
      int lo = ii < jj ? ii : jj, hi = ii < jj ? jj : ii;
      s += -1.0f + 0.1f * (float)simsum[(b * GPg + lo) * GPg + hi] * (1.0f / (1024.f * 1024.f));
    }
    simmean[b][ii] = s * (1.0f / GPg);
  }
  __syncthreads();
  if (t < NB) {
    int b = t;
    float l1v[2], l2v[2];
#pragma unroll
    for (int u = 0; u < 2; u++) {
      float s = cfb[u];
      for (int jj = 0; jj < 20; jj++) s += feat[b][jj] * cfW[jj * 2 + u];
      l1v[u] = s;
      float s2 = sfb[u];
      for (int pp = 0; pp < GPg; pp++) s2 += simmean[b][pp] * strength[b][pp] * sfW[pp * 2 + u];
      l2v[u] = s2;
    }
    float m1 = fmaxf(l1v[0], l1v[1]);
    float lse1 = m1 + logf(expf(l1v[0] - m1) + expf(l1v[1] - m1));
    float m2 = fmaxf(l2v[0], l2v[1]);
    float lse2 = m2 + logf(expf(l2v[0] - m2) + expf(l2v[1] - m2));
    out[b * 2 + 0] = 0.4f * (l1v[0] - lse1) + 0.6f * (l2v[0] - lse2);
    out[b * 2 + 1] = 0.4f * (l1v[1] - lse1) + 0.6f * (l2v[1] - lse2);
  }
}

extern "C" void kernel_launch(void* const* d_in, const int* in_sizes, int n_in,
                              void* d_out, int out_size, void* d_ws, size_t ws_size,
                              hipStream_t stream) {
  const float* x   = (const float*)d_in[0];
  const float* ea  = (const float*)d_in[1];
  const float* gW  = (const float*)d_in[2];
  const float* gb  = (const float*)d_in[3];
  const float* Ws  = (const float*)d_in[4];
  const float* l1W = (const float*)d_in[5];
  const float* l1b = (const float*)d_in[6];
  const float* cfW = (const float*)d_in[7];
  const float* cfb = (const float*)d_in[8];
  const float* l2W = (const float*)d_in[9];
  const float* l2b = (const float*)d_in[10];
  const float* sfW = (const float*)d_in[11];
  const float* sfb = (const float*)d_in[12];
  const int* eidx  = (const int*)d_in[13];
  float* out = (float*)d_out;

  char* w = (char*)d_ws;
  auto alloc = [&](size_t bytes) { char* p = w; w += (bytes + 255) & ~(size_t)255; return (void*)p; };
  bf16* gwt     = (bf16*)alloc(4 * DD * DD * 2);
  bf16* wst     = (bf16*)alloc(4 * DD * DD * 2);
  int* counts   = (int*)alloc((size_t)NG * NN * 4);        // zeroed trio: counts+gmat+simsum
  float* gmat   = (float*)alloc((size_t)NB * 768 * 4);     // (contiguous, 111168 B total)
  unsigned* simsum = (unsigned*)alloc((size_t)NB * 36 * 4);
  float* dinv4  = (float*)alloc((size_t)NG * NN * 4 * 4);
  int* offs     = (int*)alloc((size_t)NG * 1025 * 4);
  int* cursor   = (int*)alloc((size_t)NG * NN * 4);
  int* csrs     = (int*)alloc((size_t)NG * EE * 4);
  float* csre   = (float*)alloc((size_t)NG * EE * 4 * 4);
  bf16* xw      = (bf16*)alloc((size_t)NG * NN * 512 * 2);
  bf16* hb      = (bf16*)alloc((size_t)NG * NN * 512 * 2);
  bf16* xn      = (bf16*)alloc((size_t)NG * NN * DD * 2);

  k_zero<<<28, 256, 0, stream>>>((f32x4*)counts);          // 111168 B = 6948 x 16B
  k_histw<<<1792, 256, 0, stream>>>(eidx, counts, gW, Ws, gwt, wst);
  k_scan<<<NG, 1024, 0, stream>>>(counts, offs, cursor);
  k_scatter<<<(NG * EE) / 256, 256, 0, stream>>>(eidx, ea, cursor, csrs, csre);
  k_deg<<<(NG * NN * 4) / 256, 256, 0, stream>>>(offs, csre, dinv4);
  k_xw<<<NG * 4 * 8, 256, 0, stream>>>(x, gwt, dinv4, xw);
  k_agg<<<NG * 256, 256, 0, stream>>>(offs, csrs, csre, dinv4, gb, xw, hb);
  k_mixn<<<NG * 8, 256, 0, stream>>>(hb, wst, gmat, xn);
  k_pair<<<1344, 256, 0, stream>>>(xn, simsum);
  k_back<<<1, 1024, 0, stream>>>(gmat, simsum, l1W, l1b, cfW, cfb, l2W, l2b, sfW, sfb, out);
}

// Round 21
// 170.945 us; speedup vs baseline: 1.0462x; 1.0462x over previous
//
#include <hip/hip_runtime.h>

#define NG 24      // B*GP graphs
#define NB 4       // batch
#define GPg 6      // graphs per sample
#define NN 1024    // nodes
#define DD 128     // feature dim
#define EE 16384   // edges per graph

typedef __bf16 bf16;
typedef __bf16 bf16x8 __attribute__((ext_vector_type(8)));
typedef float f32x4 __attribute__((ext_vector_type(4)));

#define GLOBAL_AS __attribute__((address_space(1)))
#define LDS_AS __attribute__((address_space(3)))

// poly bin: w = 10.5*(1+tanh(s)) via deg-7 odd poly, |err(tanh)|<=6e-5 on |s|<=1.05
__device__ __forceinline__ int binidx(float v) {
  float u = v * v;
  float q = fmaf(fmaf(fmaf(-0.261093f, u, 1.222977f), u, -3.463278f), u, 10.49874f);
  return (int)fmaf(v, q, 10.5f);
}

// ---- zero counts+gmat+simsum (111168 B contiguous) ----
__global__ void k_zero(f32x4* __restrict__ p) {
  int i = blockIdx.x * 256 + threadIdx.x;
  if (i < 6948) p[i] = f32x4{0.f, 0.f, 0.f, 0.f};
}

// ---- fused: dst histogram via LDS two-level (blocks 0..1535; 64 blocks/graph,
// ---- 4KB LDS hist, global atomics 6.3M -> ~0.4M) | weight transpose (1536..1791) ----
__global__ void k_histw(const int* __restrict__ ei, int* __restrict__ counts,
                        const float* __restrict__ gW, const float* __restrict__ Ws,
                        bf16* __restrict__ gwt, bf16* __restrict__ wst) {
  int bid = blockIdx.x;
  if (bid >= 1536) {                     // weight transpose -> bf16 (block-uniform branch)
    int i = (bid - 1536) * 256 + threadIdx.x;   // i < 4*128*128
    int c = i >> 14, k = (i >> 7) & 127, j = i & 127;
    gwt[(c << 14) | (j << 7) | k] = (bf16)gW[i];   // gwt[c][j][k] = gW[c][k][j]
    wst[(j << 9) | (c << 7) | k] = (bf16)Ws[i];    // wst[j][c][k] = Ws[c][k][j]
    return;
  }
  __shared__ int lh[NN];
  int tid = threadIdx.x;
#pragma unroll
  for (int q = 0; q < 4; q++) lh[q * 256 + tid] = 0;
  __syncthreads();
  int t = bid * 256 + tid;               // t < NG*EE; g uniform per block (64 blocks/graph)
  int g = t >> 14, e = t & (EE - 1);
  int dst = ei[g * 2 * EE + EE + e];
  atomicAdd(&lh[dst], 1);
  __syncthreads();
  int* cg = counts + g * NN;
#pragma unroll
  for (int q = 0; q < 4; q++) {
    int idx = q * 256 + tid;
    int v = lh[idx];
    if (v) atomicAdd(&cg[idx], v);
  }
}

// ---------------- per-graph prefix sum (shfl wave-scan, 2 barriers) ----------------
__global__ void k_scan(const int* __restrict__ counts, int* __restrict__ offs,
                       int* __restrict__ cursor) {
  __shared__ int wsum[16];
  int g = blockIdx.x, t = threadIdx.x;   // 1024 threads = 16 waves
  int lane = t & 63, wv = t >> 6;
  int myc = counts[g * NN + t];
  int v = myc;
#pragma unroll
  for (int d = 1; d < 64; d <<= 1) {
    int u = __shfl_up(v, d);
    if (lane >= d) v += u;
  }
  if (lane == 63) wsum[wv] = v;
  __syncthreads();
  if (t < 16) {
    int s = wsum[t];
#pragma unroll
    for (int d = 1; d < 16; d <<= 1) {
      int u = __shfl_up(s, d);
      if (t >= d) s += u;
    }
    wsum[t] = s;                         // inclusive scan of wave sums
  }
  __syncthreads();
  int incl = v + (wv > 0 ? wsum[wv - 1] : 0);
  int excl = incl - myc;
  offs[g * 1025 + t] = excl;
  cursor[g * NN + t] = excl;
  if (t == NN - 1) offs[g * 1025 + NN] = incl;
}

// ---------------- CSR scatter: src index + raw edge weights (vectorized) ----------------
__global__ void k_scatter(const int* __restrict__ ei, const float* __restrict__ ea,
                          int* __restrict__ cursor, int* __restrict__ csrs,
                          float* __restrict__ csre) {
  int t = blockIdx.x * 256 + threadIdx.x;
  if (t >= NG * EE) return;
  int g = t >> 14, e = t & (EE - 1);
  int src = ei[g * 2 * EE + e], dst = ei[g * 2 * EE + EE + e];
  int pos = atomicAdd(&cursor[g * NN + dst], 1);
  size_t idx = (size_t)g * EE + pos;
  csrs[idx] = src;
  const float* p = ea + ((size_t)g * EE + e) * 6;
  float2 q0 = *(const float2*)(p + 2);   // 8B-aligned (24e+8)
  float2 q1 = *(const float2*)(p + 4);
  f32x4 v; v[0] = q0.x; v[1] = q0.y; v[2] = q1.x; v[3] = q1.y;
  *(f32x4*)(csre + idx * 4) = v;
}

// ---------------- per-node degree -> dinv4[g][n][4] (CSR row walk) ----------------
__global__ void k_deg(const int* __restrict__ offs, const float* __restrict__ csre,
                      float* __restrict__ dinv4) {
  int t = blockIdx.x * 256 + threadIdx.x;   // t = ((g*NN)+n)*4+c
  int c = t & 3, n = (t >> 2) & (NN - 1), g = t >> 12;
  int beg = offs[g * 1025 + n], end = offs[g * 1025 + n + 1];
  const float* ep = csre + (size_t)g * EE * 4 + c;
  float s = 1.0f;                            // self loop
  for (int p = beg; p < end; ++p) s += ep[(size_t)p * 4];
  dinv4[t] = rsqrtf(s);
}

// ------- xws[g][n][c*128+j] = dinv4[g][n][c] * (x[g] @ gW[c])[n][j]  (f32 A, bf16 MFMA) -------
__global__ __launch_bounds__(256) void k_xw(const float* __restrict__ x,
                                            const bf16* __restrict__ gwt,
                                            const float* __restrict__ dinv4,
                                            bf16* __restrict__ xw) {
  int bid = blockIdx.x;
  int gc = bid >> 3, mb = bid & 7;
  int g = gc >> 2, c = gc & 3;
  int lane = threadIdx.x & 63, wid = threadIdx.x >> 6;
  int wm = wid >> 1, wn = wid & 1;
  int row0 = mb * 128 + wm * 64, col0 = wn * 64;
  const float* A = x + (size_t)g * NN * DD;
  const bf16* Bt = gwt + (size_t)c * DD * DD;
  int lr = lane & 15, lk = (lane >> 4) * 8;
  f32x4 acc[4][4] = {};
  for (int kc = 0; kc < 128; kc += 32) {
    bf16x8 a[4], b[4];
#pragma unroll
    for (int i2 = 0; i2 < 4; i2++) {
      const f32x4* pa = (const f32x4*)(A + (size_t)(row0 + i2 * 16 + lr) * DD + kc + lk);
      f32x4 f0 = pa[0], f1 = pa[1];
#pragma unroll
      for (int q = 0; q < 4; q++) { a[i2][q] = (bf16)f0[q]; a[i2][4 + q] = (bf16)f1[q]; }
    }
#pragma unroll
    for (int j2 = 0; j2 < 4; j2++)
      b[j2] = *(const bf16x8*)(Bt + (size_t)(col0 + j2 * 16 + lr) * DD + kc + lk);
#pragma unroll
    for (int i2 = 0; i2 < 4; i2++)
#pragma unroll
      for (int j2 = 0; j2 < 4; j2++)
        acc[i2][j2] = __builtin_amdgcn_mfma_f32_16x16x32_bf16(a[i2], b[j2], acc[i2][j2], 0, 0, 0);
  }
  bf16* out = xw + (size_t)g * NN * 512 + c * 128;
  const float* dv = dinv4 + ((size_t)g * NN) * 4 + c;
  int cr = (lane >> 4) * 4, cc = lane & 15;
#pragma unroll
  for (int i2 = 0; i2 < 4; i2++)
#pragma unroll
    for (int r2 = 0; r2 < 4; r2++) {
      int row = row0 + i2 * 16 + cr + r2;
      float dvv = dv[row * 4];
#pragma unroll
      for (int j2 = 0; j2 < 4; j2++)
        out[(size_t)row * 512 + col0 + j2 * 16 + cc] = (bf16)(acc[i2][j2][r2] * dvv);
    }
}

// ---- aggregation: hb[g][n][512] = relu(dinv*(sum ew*xws[src] + xws[n]) + b), 4 ch/wave,
// ---- 4-deep gather pipeline ----
__global__ __launch_bounds__(256) void k_agg(const int* __restrict__ offs, const int* __restrict__ csrs,
                                             const float* __restrict__ csre, const float* __restrict__ dinv4,
                                             const float* __restrict__ gb, const bf16* __restrict__ xw,
                                             bf16* __restrict__ hb) {
  int bid = blockIdx.x;
  int lb = (bid & 7) * (NG * 256 / 8) + (bid >> 3);   // XCD swizzle: 768 blocks (3 graphs) per XCD
  int g = lb >> 8, n4 = lb & 255;
  int wid = threadIdx.x >> 6, lane = threadIdx.x & 63;
  int n = n4 * 4 + wid;
  int c = lane >> 4, d0 = (lane & 15) * 8;
  const bf16* xwg = xw + (size_t)g * NN * 512;
  int beg = offs[g * 1025 + n], end = offs[g * 1025 + n + 1];
  const int* sp = csrs + (size_t)g * EE;
  const float* ep = csre + (size_t)g * EE * 4;
  float dvn = dinv4[((size_t)g * NN + n) * 4 + c];
  float acc[8] = {};
  int p = beg;
  for (; p + 3 < end; p += 4) {
    int s0 = sp[p], s1 = sp[p + 1], s2 = sp[p + 2], s3 = sp[p + 3];
    float w0 = ep[(size_t)p * 4 + c];
    float w1 = ep[(size_t)(p + 1) * 4 + c];
    float w2 = ep[(size_t)(p + 2) * 4 + c];
    float w3 = ep[(size_t)(p + 3) * 4 + c];
    bf16x8 v0 = *(const bf16x8*)(xwg + (size_t)s0 * 512 + lane * 8);
    bf16x8 v1 = *(const bf16x8*)(xwg + (size_t)s1 * 512 + lane * 8);
    bf16x8 v2 = *(const bf16x8*)(xwg + (size_t)s2 * 512 + lane * 8);
    bf16x8 v3 = *(const bf16x8*)(xwg + (size_t)s3 * 512 + lane * 8);
#pragma unroll
    for (int q = 0; q < 8; q++)
      acc[q] += w0 * (float)v0[q] + w1 * (float)v1[q] + w2 * (float)v2[q] + w3 * (float)v3[q];
  }
  for (; p < end; ++p) {
    int s0 = sp[p];
    float w0 = ep[(size_t)p * 4 + c];
    bf16x8 v0 = *(const bf16x8*)(xwg + (size_t)s0 * 512 + lane * 8);
#pragma unroll
    for (int q = 0; q < 8; q++) acc[q] += w0 * (float)v0[q];
  }
  bf16x8 vs = *(const bf16x8*)(xwg + (size_t)n * 512 + lane * 8);
  bf16x8 o;
#pragma unroll
  for (int q = 0; q < 8; q++) {
    float r2 = dvn * (acc[q] + (float)vs[q]) + gb[c * 128 + d0 + q];
    o[q] = (bf16)fmaxf(r2, 0.f);
  }
  *(bf16x8*)(hb + ((size_t)g * NN + n) * 512 + lane * 8) = o;
}

// ---- fused: x_tmp = hb @ wst (K=512); row-mean -> gmat; row-L2-normalize -> xn (bf16) ----
__global__ __launch_bounds__(256) void k_mixn(const bf16* __restrict__ hb,
                                              const bf16* __restrict__ wst,
                                              float* __restrict__ gmat,
                                              bf16* __restrict__ xn) {
  __shared__ float rowssq[128];
  int bid = blockIdx.x;
  int g = bid >> 3, mb = bid & 7;
  int lane = threadIdx.x & 63, wid = threadIdx.x >> 6;
  int wm = wid >> 1, wn = wid & 1;
  int row0 = mb * 128 + wm * 64, col0 = wn * 64;
  const bf16* H = hb + (size_t)g * NN * 512;
  int lr = lane & 15, lk = (lane >> 4) * 8;
  if (threadIdx.x < 128) rowssq[threadIdx.x] = 0.f;
  f32x4 acc[4][4] = {};
  for (int kc = 0; kc < 512; kc += 32) {
    bf16x8 a[4], b[4];
#pragma unroll
    for (int i2 = 0; i2 < 4; i2++)
      a[i2] = *(const bf16x8*)(H + (size_t)(row0 + i2 * 16 + lr) * 512 + kc + lk);
#pragma unroll
    for (int j2 = 0; j2 < 4; j2++)
      b[j2] = *(const bf16x8*)(wst + (size_t)(col0 + j2 * 16 + lr) * 512 + kc + lk);
#pragma unroll
    for (int i2 = 0; i2 < 4; i2++)
#pragma unroll
      for (int j2 = 0; j2 < 4; j2++)
        acc[i2][j2] = __builtin_amdgcn_mfma_f32_16x16x32_bf16(a[i2], b[j2], acc[i2][j2], 0, 0, 0);
  }
  __syncthreads();                       // rowssq zeros visible
  int cr = (lane >> 4) * 4, cc = lane & 15;
#pragma unroll
  for (int i2 = 0; i2 < 4; i2++)
#pragma unroll
    for (int r2 = 0; r2 < 4; r2++) {
      float s = 0.f;
#pragma unroll
      for (int j2 = 0; j2 < 4; j2++) { float v = acc[i2][j2][r2]; s += v * v; }
#pragma unroll
      for (int d2 = 1; d2 < 16; d2 <<= 1) s += __shfl_xor(s, d2);
      if (cc == 0) atomicAdd(&rowssq[wm * 64 + i2 * 16 + cr + r2], s);
    }
#pragma unroll
  for (int j2 = 0; j2 < 4; j2++) {
    float s = 0.f;
#pragma unroll
    for (int i2 = 0; i2 < 4; i2++)
#pragma unroll
      for (int r2 = 0; r2 < 4; r2++) s += acc[i2][j2][r2];
    s += __shfl_xor(s, 16);
    s += __shfl_xor(s, 32);
    if ((lane >> 4) == 0)
      atomicAdd(&gmat[(g / GPg) * 768 + (g % GPg) * 128 + col0 + j2 * 16 + cc], s * (1.0f / NN));
  }
  __syncthreads();                       // rowssq complete
  bf16* xp = xn + (size_t)g * NN * DD;
#pragma unroll
  for (int i2 = 0; i2 < 4; i2++)
#pragma unroll
    for (int r2 = 0; r2 < 4; r2++) {
      int rowl = wm * 64 + i2 * 16 + cr + r2;
      float inv = 1.0f / fmaxf(sqrtf(rowssq[rowl]), 1e-12f);
#pragma unroll
      for (int j2 = 0; j2 < 4; j2++)
        xp[(size_t)(mb * 128 + rowl) * DD + col0 + j2 * 16 + cc] = (bf16)(acc[i2][j2][r2] * inv);
    }
}

// ---- pairwise sim: (pair, 128-row strip, 16-tile half) per block; 2x8KB LDS dbuf,
// ---- fragment-order LDS (0 conflicts), counted-vmcnt pipeline, diagonal symmetry,
// ---- POLY binning ----
__global__ __launch_bounds__(256, 4) void k_pair(const bf16* __restrict__ xn,
                                                 unsigned* __restrict__ simsum) {
  __shared__ char lds[16384];            // 2 x 8KB B-tile (32 cols x 128 k)
  int bid = blockIdx.x;
  int lb = (bid & 7) * 168 + (bid >> 3); // 1344 = 8*168, bijective XCD swizzle
  int b = lb / 336, rem = lb % 336;
  int pj = rem >> 4, rem2 = rem & 15;
  int s128 = rem2 >> 1, half = rem2 & 1; // 128-row strip, 16-tile half of B range
  int r = pj, i = 0;
  while (r >= 6 - i) { r -= 6 - i; ++i; }
  int j = i + r;
  bool isdiag = (i == j);
  int tb = half * 16, te = tb + 16;
  if (isdiag && 4 * s128 > tb) tb = 4 * s128;   // diagonal: skip tiles below the diagonal
  if (tb >= te) return;                          // empty half
  int lane = threadIdx.x & 63, wid = threadIdx.x >> 6;
  int lr = lane & 15, hi16 = (lane >> 4) * 16;
  const char* Ag = (const char*)(xn + ((size_t)(b * GPg + i) * NN + s128 * 128 + wid * 32) * DD);
  const char* Bg0 = (const char*)(xn + (size_t)(b * GPg + j) * NN * DD);

  // A: wave's 32 rows x 128 k in registers, forced-complete before staging (vmcnt bookkeeping)
  bf16x8 a[2][4];
#pragma unroll
  for (int g2 = 0; g2 < 2; g2++)
#pragma unroll
    for (int kc = 0; kc < 4; kc++) {
      a[g2][kc] = *(const bf16x8*)(Ag + (g2 * 16 + lr) * 256 + kc * 64 + hi16);
      asm volatile("" :: "v"(a[g2][kc]));
    }

  // stage 8KB tile tn (32 B-rows x 256B) in fragment order; wave wid owns kc=wid:
  // LDS slot (kc*2048 + j2*1024 + lane*16) <- global row=(j2*16+lr), kbyte=kc*64+hi16
  auto stage = [&](int buf, int tn) {
    const char* src = Bg0 + tn * 8192;
#pragma unroll
    for (int j2 = 0; j2 < 2; ++j2)
      __builtin_amdgcn_global_load_lds(
          (const GLOBAL_AS void*)(src + (j2 * 16 + lr) * 256 + wid * 64 + hi16),
          (LDS_AS void*)(lds + buf * 8192 + wid * 2048 + j2 * 1024), 16, 0, 0);
  };
  stage(0, tb);
  if (tb + 1 < te) stage(1, tb + 1);

  int cnt = 0;
  int cc = lane & 15, cr = (lane >> 4) * 4;
  for (int t = tb; t < te; ++t) {
    int cur = (t - tb) & 1;
    if (t < te - 1) asm volatile("s_waitcnt vmcnt(2)" ::: "memory");  // buf[cur] ready; next in flight
    else            asm volatile("s_waitcnt vmcnt(0)" ::: "memory");
    __builtin_amdgcn_s_barrier();
    const char* Bl = lds + cur * 8192;
    f32x4 acc[2][2] = {};
#pragma unroll
    for (int kc = 0; kc < 4; kc++) {
      bf16x8 bb[2];
#pragma unroll
      for (int j2 = 0; j2 < 2; j2++)
        bb[j2] = *(const bf16x8*)(Bl + kc * 2048 + j2 * 1024 + lane * 16);  // conflict-free
#pragma unroll
      for (int g2 = 0; g2 < 2; g2++)
#pragma unroll
        for (int j2 = 0; j2 < 2; j2++)
          acc[g2][j2] = __builtin_amdgcn_mfma_f32_16x16x32_bf16(a[g2][kc], bb[j2], acc[g2][j2], 0, 0, 0);
    }
    asm volatile("s_waitcnt lgkmcnt(0)" ::: "memory");  // my ds_reads done before buffer reuse
    __builtin_amdgcn_sched_barrier(0);
    __builtin_amdgcn_s_barrier();        // all waves done reading buf[cur]
    if (t + 2 < te) stage(cur, t + 2);   // refill; flight hidden under binning + next MFMA
    if (isdiag && t < 4 * s128 + 4) {    // boundary tiles: per-element 2/1/0 weights
      int tc = 0;
#pragma unroll
      for (int g2 = 0; g2 < 2; g2++)
#pragma unroll
        for (int j2 = 0; j2 < 2; j2++)
#pragma unroll
          for (int r2 = 0; r2 < 4; r2++) {
            int idx = binidx(acc[g2][j2][r2]);
            int lm = t * 32 + j2 * 16 + cc;
            int ln = s128 * 128 + wid * 32 + g2 * 16 + cr + r2;
            tc += (lm > ln) ? 2 * idx : (lm == ln ? idx : 0);
          }
      cnt += tc;
    } else {
      int tc = 0;
#pragma unroll
      for (int g2 = 0; g2 < 2; g2++)
#pragma unroll
        for (int j2 = 0; j2 < 2; j2++)
#pragma unroll
          for (int r2 = 0; r2 < 4; r2++)
            tc += binidx(acc[g2][j2][r2]);
      cnt += isdiag ? 2 * tc : tc;       // wave-uniform weight
    }
  }
#pragma unroll
  for (int d2 = 32; d2; d2 >>= 1) cnt += __shfl_xor(cnt, d2);
  if (lane == 0) atomicAdd(&simsum[((size_t)b * GPg + i) * GPg + j], (unsigned)cnt);
}

// ---------------- backnet: 104 length-768 dots, 8 threads each ----------------
__global__ void k_back(const float* __restrict__ gmat, const unsigned* __restrict__ simsum,
                       const float* __restrict__ l1W, const float* __restrict__ l1b,
                       const float* __restrict__ cfW, const float* __restrict__ cfb,
                       const float* __restrict__ l2W, const float* __restrict__ l2b,
                       const float* __restrict__ sfW, const float* __restrict__ sfb,
                       float* __restrict__ out) {
  __shared__ float feat[NB][20];
  __shared__ float strength[NB][GPg];
  __shared__ float simmean[NB][GPg];
  int t = threadIdx.x, g = t >> 3, l = t & 7;
  if (g < 80) {                          // feat: 4x20 dots of length 768
    int b = g / 20, jj = g % 20;
    float s = 0.f;
#pragma unroll 8
    for (int k = l; k < 768; k += 8) s += gmat[b * 768 + k] * l1W[k * 20 + jj];
    s += __shfl_xor(s, 1); s += __shfl_xor(s, 2); s += __shfl_xor(s, 4);
    if (l == 0) {
      float f = fmaxf(s + l1b[jj], 0.f);
      feat[b][jj] = f;
      out[8 + b * 20 + jj] = f;
    }
  } else if (g < 104) {                  // strength: 4x6 dots of length 768
    int q = g - 80, b = q / GPg, pp = q % GPg;
    float s = 0.f;
#pragma unroll 8
    for (int k = l; k < 768; k += 8) s += gmat[b * 768 + k] * l2W[k * GPg + pp];
    s += __shfl_xor(s, 1); s += __shfl_xor(s, 2); s += __shfl_xor(s, 4);
    if (l == 0) strength[b][pp] = s + l2b[pp];
  } else if (t >= 832 && t < 856) {      // simmean from simsum
    int q = t - 832; int b = q / GPg, ii = q % GPg;
    float s = 0.f;
    for (int jj = 0; jj < GPg; jj++) {
      int lo = ii < jj ? ii : jj, hi = ii < jj ? jj : ii;
      s += -1.0f + 0.1f * (float)simsum[(b * GPg + lo) * GPg + hi] * (1.0f / (1024.f * 1024.f));
    }
    simmean[b][ii] = s * (1.0f / GPg);
  }
  __syncthreads();
  if (t < NB) {
    int b = t;
    float l1v[2], l2v[2];
#pragma unroll
    for (int u = 0; u < 2; u++) {
      float s = cfb[u];
      for (int jj = 0; jj < 20; jj++) s += feat[b][jj] * cfW[jj * 2 + u];
      l1v[u] = s;
      float s2 = sfb[u];
      for (int pp = 0; pp < GPg; pp++) s2 += simmean[b][pp] * strength[b][pp] * sfW[pp * 2 + u];
      l2v[u] = s2;
    }
    float m1 = fmaxf(l1v[0], l1v[1]);
    float lse1 = m1 + logf(expf(l1v[0] - m1) + expf(l1v[1] - m1));
    float m2 = fmaxf(l2v[0], l2v[1]);
    float lse2 = m2 + logf(expf(l2v[0] - m2) + expf(l2v[1] - m2));
    out[b * 2 + 0] = 0.4f * (l1v[0] - lse1) + 0.6f * (l2v[0] - lse2);
    out[b * 2 + 1] = 0.4f * (l1v[1] - lse1) + 0.6f * (l2v[1] - lse2);
  }
}

extern "C" void kernel_launch(void* const* d_in, const int* in_sizes, int n_in,
                              void* d_out, int out_size, void* d_ws, size_t ws_size,
                              hipStream_t stream) {
  const float* x   = (const float*)d_in[0];
  const float* ea  = (const float*)d_in[1];
  const float* gW  = (const float*)d_in[2];
  const float* gb  = (const float*)d_in[3];
  const float* Ws  = (const float*)d_in[4];
  const float* l1W = (const float*)d_in[5];
  const float* l1b = (const float*)d_in[6];
  const float* cfW = (const float*)d_in[7];
  const float* cfb = (const float*)d_in[8];
  const float* l2W = (const float*)d_in[9];
  const float* l2b = (const float*)d_in[10];
  const float* sfW = (const float*)d_in[11];
  const float* sfb = (const float*)d_in[12];
  const int* eidx  = (const int*)d_in[13];
  float* out = (float*)d_out;

  char* w = (char*)d_ws;
  auto alloc = [&](size_t bytes) { char* p = w; w += (bytes + 255) & ~(size_t)255; return (void*)p; };
  bf16* gwt     = (bf16*)alloc(4 * DD * DD * 2);
  bf16* wst     = (bf16*)alloc(4 * DD * DD * 2);
  int* counts   = (int*)alloc((size_t)NG * NN * 4);        // zeroed trio: counts+gmat+simsum
  float* gmat   = (float*)alloc((size_t)NB * 768 * 4);     // (contiguous, 111168 B total)
  unsigned* simsum = (unsigned*)alloc((size_t)NB * 36 * 4);
  float* dinv4  = (float*)alloc((size_t)NG * NN * 4 * 4);
  int* offs     = (int*)alloc((size_t)NG * 1025 * 4);
  int* cursor   = (int*)alloc((size_t)NG * NN * 4);
  int* csrs     = (int*)alloc((size_t)NG * EE * 4);
  float* csre   = (float*)alloc((size_t)NG * EE * 4 * 4);
  bf16* xw      = (bf16*)alloc((size_t)NG * NN * 512 * 2);
  bf16* hb      = (bf16*)alloc((size_t)NG * NN * 512 * 2);
  bf16* xn      = (bf16*)alloc((size_t)NG * NN * DD * 2);

  k_zero<<<28, 256, 0, stream>>>((f32x4*)counts);          // 111168 B = 6948 x 16B
  k_histw<<<1792, 256, 0, stream>>>(eidx, counts, gW, Ws, gwt, wst);
  k_scan<<<NG, 1024, 0, stream>>>(counts, offs, cursor);
  k_scatter<<<(NG * EE) / 256, 256, 0, stream>>>(eidx, ea, cursor, csrs, csre);
  k_deg<<<(NG * NN * 4) / 256, 256, 0, stream>>>(offs, csre, dinv4);
  k_xw<<<NG * 4 * 8, 256, 0, stream>>>(x, gwt, dinv4, xw);
  k_agg<<<NG * 256, 256, 0, stream>>>(offs, csrs, csre, dinv4, gb, xw, hb);
  k_mixn<<<NG * 8, 256, 0, stream>>>(hb, wst, gmat, xn);
  k_pair<<<1344, 256, 0, stream>>>(xn, simsum);
  k_back<<<1, 1024, 0, stream>>>(gmat, simsum, l1W, l1b, cfW, cfb, l2W, l2b, sfW, sfb, out);
}